// Round 1
// baseline (150.132 us; speedup 1.0000x reference)
//
#include <hip/hip_runtime.h>
#include <hip/hip_bf16.h>
#include <stdint.h>

// Problem: P=128 proxy sets x E=32 elements x D=64; N=131072 x-rows in B=1024
// segments (length given by `index`, =128 each here).
//   pooled[b,p] = sum_{n in seg b} max_e ( proxy[p,e,:] . x[n,:] )
//   out = L2-row-normalized pooled  [B, P] fp32
//
// Strategy: bf16 MFMA (threshold 1.97e-3 >> bf16-induced ~3e-5 output error).
// Per block: one segment x all 128 p. Per wave: full segment (4 N-tiles x 4
// K-steps of v_mfma_f32_32x32x16_bf16), loop 32 p's with double-buffered
// A-frags from L2-resident bf16 proxy (pre-converted in ws). max-over-e and
// sum-over-n fused in registers via the m74/m101-verified C/D layout:
//   col = lane&31 (n), row = (reg&3) + 8*(reg>>2) + 4*(lane>>5) (e).

typedef short short8 __attribute__((ext_vector_type(8)));
typedef __bf16 bf16x8 __attribute__((ext_vector_type(8)));
typedef float floatx16 __attribute__((ext_vector_type(16)));

#define NPROXY 128
#define NELEM  32
#define DIM    64
#define NSEG   1024
#define PROXY_ELEMS (NPROXY * NELEM * DIM) /* 262144 */

__device__ __forceinline__ unsigned short f32_to_bf16_rne(float f) {
  union { float f; unsigned int u; } v; v.f = f;
  unsigned int r = v.u + 0x7fffu + ((v.u >> 16) & 1u);
  return (unsigned short)(r >> 16);
}

// Block 0: exclusive-scan of segment lengths -> offs[0..NSEG] (handles general
// ragged input). Blocks 1..256: proxy fp32 -> bf16 into ws. Blocks 1..128 also
// zero d_out (needed only for the multi-chunk atomicAdd path; cheap).
__global__ void sc_prep(const float* __restrict__ proxy,
                        const int* __restrict__ index,
                        short* __restrict__ pb,
                        int* __restrict__ offs,
                        float* __restrict__ out) {
  const int bx = blockIdx.x, t = threadIdx.x;
  if (bx == 0) {
    __shared__ int lsum[256];
    const int base = t * 4;
    const int i0 = index[base + 0], i1 = index[base + 1];
    const int i2 = index[base + 2], i3 = index[base + 3];
    const int s = i0 + i1 + i2 + i3;
    lsum[t] = s;
    __syncthreads();
    for (int off = 1; off < 256; off <<= 1) {
      int v = (t >= off) ? lsum[t - off] : 0;
      __syncthreads();
      lsum[t] += v;
      __syncthreads();
    }
    const int ex = lsum[t] - s; // exclusive prefix
    offs[base + 0] = ex;
    offs[base + 1] = ex + i0;
    offs[base + 2] = ex + i0 + i1;
    offs[base + 3] = ex + i0 + i1 + i2;
    if (t == 255) offs[NSEG] = ex + s;
  } else {
    const int idx = ((bx - 1) * 256 + t) * 4; // covers 262144 elems
    float4 v = *(const float4*)(proxy + idx);
    ushort4 o;
    o.x = f32_to_bf16_rne(v.x); o.y = f32_to_bf16_rne(v.y);
    o.z = f32_to_bf16_rne(v.z); o.w = f32_to_bf16_rne(v.w);
    *(ushort4*)(pb + idx) = o;
    if (bx <= 128) {
      const int oidx = ((bx - 1) * 256 + t) * 4; // covers 131072 outs
      *(float4*)(out + oidx) = make_float4(0.f, 0.f, 0.f, 0.f);
    }
  }
}

__global__ __launch_bounds__(256, 2) void sc_main(
    const float* __restrict__ x,
    const short* __restrict__ pb,
    const int* __restrict__ offs,
    float* __restrict__ out) {
  const int b = blockIdx.x;
  const int tid = threadIdx.x;
  const int lane = tid & 63;
  const int w = tid >> 6;      // wave 0..3: handles p = w, w+4, ..., w+124
  const int l31 = lane & 31;   // MFMA row (A: e) / col (B: n)
  const int h = lane >> 5;     // k-half: k = 16*kk + 8*h + i

  const int start = offs[b];
  const int len = offs[b + 1] - start;
  const int nchunks = (len + 127) >> 7;
  const bool single_chunk = (nchunks == 1);

  // A-frag base for this lane: pb[p][e=l31][k = 8h + ...]
  const short* pbase = pb + l31 * DIM + h * 8;

  for (int c = 0; c < nchunks; ++c) {
    const int c0 = c << 7;

    // B-frags: x rows of this segment chunk, fp32 -> bf16 in-register.
    // B[k][n]: lane holds n = l31 (tile col), k = 16*kk + 8*h + i.
    short8 bfrag[4][4];
#pragma unroll
    for (int t4 = 0; t4 < 4; ++t4) {
      const int nl = c0 + t4 * 32 + l31;
      const bool valid = (nl < len); // zero-pad cols contribute max_e(0)=0
      const float* xr = x + (size_t)(start + nl) * DIM + h * 8;
#pragma unroll
      for (int kk = 0; kk < 4; ++kk) {
        float4 f0 = make_float4(0.f, 0.f, 0.f, 0.f), f1 = f0;
        if (valid) {
          f0 = *(const float4*)(xr + kk * 16);
          f1 = *(const float4*)(xr + kk * 16 + 4);
        }
        short8 fr;
        fr[0] = (short)f32_to_bf16_rne(f0.x);
        fr[1] = (short)f32_to_bf16_rne(f0.y);
        fr[2] = (short)f32_to_bf16_rne(f0.z);
        fr[3] = (short)f32_to_bf16_rne(f0.w);
        fr[4] = (short)f32_to_bf16_rne(f1.x);
        fr[5] = (short)f32_to_bf16_rne(f1.y);
        fr[6] = (short)f32_to_bf16_rne(f1.z);
        fr[7] = (short)f32_to_bf16_rne(f1.w);
        bfrag[t4][kk] = fr;
      }
    }

    auto process_p = [&](int p, short8 (&acur)[4], short8 (&anxt)[4], bool pf) {
      if (pf) { // prefetch A-frags for p+4 (double buffer, hides ~200cy L2 hit)
        const short* ap = pbase + (size_t)(p + 4) * (NELEM * DIM);
#pragma unroll
        for (int kk = 0; kk < 4; ++kk)
          anxt[kk] = *(const short8*)(ap + kk * 16);
      }
      floatx16 acc0, acc1, acc2, acc3;
#pragma unroll
      for (int r = 0; r < 16; ++r) {
        acc0[r] = 0.f; acc1[r] = 0.f; acc2[r] = 0.f; acc3[r] = 0.f;
      }
#pragma unroll
      for (int kk = 0; kk < 4; ++kk) {
        bf16x8 a = __builtin_bit_cast(bf16x8, acur[kk]);
        acc0 = __builtin_amdgcn_mfma_f32_32x32x16_bf16(
            a, __builtin_bit_cast(bf16x8, bfrag[0][kk]), acc0, 0, 0, 0);
        acc1 = __builtin_amdgcn_mfma_f32_32x32x16_bf16(
            a, __builtin_bit_cast(bf16x8, bfrag[1][kk]), acc1, 0, 0, 0);
        acc2 = __builtin_amdgcn_mfma_f32_32x32x16_bf16(
            a, __builtin_bit_cast(bf16x8, bfrag[2][kk]), acc2, 0, 0, 0);
        acc3 = __builtin_amdgcn_mfma_f32_32x32x16_bf16(
            a, __builtin_bit_cast(bf16x8, bfrag[3][kk]), acc3, 0, 0, 0);
      }
      // max over e: 16 in-lane rows, then the complementary 16 from lane^32
      float m0 = acc0[0], m1 = acc1[0], m2 = acc2[0], m3 = acc3[0];
#pragma unroll
      for (int r = 1; r < 16; ++r) {
        m0 = fmaxf(m0, acc0[r]); m1 = fmaxf(m1, acc1[r]);
        m2 = fmaxf(m2, acc2[r]); m3 = fmaxf(m3, acc3[r]);
      }
      m0 = fmaxf(m0, __shfl_xor(m0, 32, 64));
      m1 = fmaxf(m1, __shfl_xor(m1, 32, 64));
      m2 = fmaxf(m2, __shfl_xor(m2, 32, 64));
      m3 = fmaxf(m3, __shfl_xor(m3, 32, 64));
      // sum over n: 4 tiles then 32 cols (xor-tree within each 32-lane half)
      float s = (m0 + m1) + (m2 + m3);
#pragma unroll
      for (int off = 1; off <= 16; off <<= 1) s += __shfl_xor(s, off, 64);
      if (lane == 0) {
        float* dst = out + (b << 7) + p;
        if (single_chunk) *dst = s;   // bench path: len==128, 1 chunk
        else atomicAdd(dst, s);       // generic ragged path (out pre-zeroed)
      }
    };

    short8 afA[4], afB[4];
    {
      const short* ap = pbase + (size_t)w * (NELEM * DIM);
#pragma unroll
      for (int kk = 0; kk < 4; ++kk)
        afA[kk] = *(const short8*)(ap + kk * 16);
    }
    // unroll-by-2 so the A double-buffer index is compile-time (no scratch)
    for (int i = 0; i < 32; i += 2) {
      process_p(w + 4 * i, afA, afB, true);
      process_p(w + 4 * (i + 1), afB, afA, i < 30);
    }
  }
}

// In-place row L2-normalize: out[b,:] /= max(||out[b,:]||_2, 1e-12)
__global__ void sc_norm(float* __restrict__ out) {
  const int b = blockIdx.x;
  const int t = threadIdx.x; // 128 threads = 2 waves
  const float v = out[(b << 7) + t];
  float sq = v * v;
#pragma unroll
  for (int off = 1; off <= 32; off <<= 1) sq += __shfl_xor(sq, off, 64);
  __shared__ float wsum[2];
  if ((t & 63) == 0) wsum[t >> 6] = sq;
  __syncthreads();
  const float denom = fmaxf(sqrtf(wsum[0] + wsum[1]), 1e-12f);
  out[(b << 7) + t] = v / denom;
}

extern "C" void kernel_launch(void* const* d_in, const int* in_sizes, int n_in,
                              void* d_out, int out_size, void* d_ws, size_t ws_size,
                              hipStream_t stream) {
  (void)in_sizes; (void)n_in; (void)out_size; (void)ws_size;
  const float* x = (const float*)d_in[0];      // [N, 64] fp32
  const float* proxy = (const float*)d_in[1];  // [128, 32, 64] fp32
  const int* index = (const int*)d_in[2];      // [1024] int32 segment lengths
  float* out = (float*)d_out;                  // [1024, 128] fp32

  int* offs = (int*)d_ws;                      // (NSEG+1) ints
  short* pb = (short*)((char*)d_ws + 8192);    // 512 KB bf16 proxy (L2-resident)

  sc_prep<<<257, 256, 0, stream>>>(proxy, index, pb, offs, out);
  sc_main<<<NSEG, 256, 0, stream>>>(x, pb, offs, out);
  sc_norm<<<NSEG, 128, 0, stream>>>(out);
}